// Round 10
// baseline (457.120 us; speedup 1.0000x reference)
//
#include <hip/hip_runtime.h>
#include <math.h>

// Problem constants
constexpr int BQ = 32;       // query batch
constexpr int C  = 256;      // channels
constexpr int HW = 4096;     // 64*64
constexpr int W  = 64;
constexpr int P  = 256;      // protos (4 * 8 * 8)
constexpr float THRESH = 0.95f;
constexpr float SCALE  = 20.0f;
constexpr float EPSF   = 1e-4f;
constexpr double EPSD  = 1e-4;
constexpr float GAP_THRESH = 2e-3f;   // split-bf16 dist err ~5e-4 -> 4x margin
constexpr int MAXSUS = 65536;

// d_out layout: pred [0, 131072) | debug_assign [131072, 262144) | proto_grid [262144, 278528)
constexpr int OUT_ASSIGN = BQ * HW;
constexpr int OUT_GRID   = 2 * BQ * HW;

typedef __attribute__((ext_vector_type(8))) short short8;
typedef __attribute__((ext_vector_type(4))) float floatx4;

static __device__ __forceinline__ unsigned short f2bf(float x) {
    unsigned u = __float_as_uint(x);
    u += 0x7FFFu + ((u >> 16) & 1u);     // round-to-nearest-even (no NaN inputs)
    return (unsigned short)(u >> 16);
}
static __device__ __forceinline__ float bf2f(unsigned short h) {
    return __uint_as_float(((unsigned)h) << 16);
}

// Fragment-order offset (ushort units): [tile][ks][h][lane][j], lane = quad*16 + idx,
// element j of lane <-> k = ks*32 + quad*8 + j. A and B use the IDENTICAL map, so
// any k-permutation cancels in the MFMA contraction.
#define FRAGOFF(tile, ks, h, lane) (((((tile) * 8 + (ks)) * 2 + (h)) * 64 + (lane)) * 8)

// async global->LDS, 16 B/lane; LDS dest = wave-uniform base + lane*16
static __device__ __forceinline__ void gl_lds16(const unsigned short* gp, unsigned short* lp) {
    __builtin_amdgcn_global_load_lds(
        (const __attribute__((address_space(1))) unsigned int*)gp,
        (__attribute__((address_space(3))) unsigned int*)lp, 16, 0, 0);
}

// ---------------------------------------------------------------------------
// Prep: pooled protos (fp64 normalize) -> split-bf16 frag-order pB + fp64 pn64,
// valid flags, proto_grid output, zero suspect counter. Block=proto, thread=channel.
// ---------------------------------------------------------------------------
__global__ __launch_bounds__(256)
void prep_kernel(const float* __restrict__ sup_x, const float* __restrict__ sup_y,
                 float* __restrict__ out, unsigned short* __restrict__ pB,
                 double* __restrict__ pn64, int* __restrict__ valid,
                 int* __restrict__ counter)
{
    const int p = blockIdx.x;     // proto index = s*64 + gy*8 + gx
    const int t = threadIdx.x;    // channel
    const int s = p >> 6, gy = (p >> 3) & 7, gx = p & 7;

    const float* base = sup_x + ((size_t)(s * C + t)) * HW + (gy * 8) * W + gx * 8;
    double sum = 0.0;
#pragma unroll
    for (int r = 0; r < 8; ++r) {
        const float4 a  = *(const float4*)(base + r * W);
        const float4 bq = *(const float4*)(base + r * W + 4);
        sum += (double)a.x;  sum += (double)a.y;  sum += (double)a.z;  sum += (double)a.w;
        sum += (double)bq.x; sum += (double)bq.y; sum += (double)bq.z; sum += (double)bq.w;
    }
    const double mean = sum * (1.0 / 64.0);

    __shared__ double red[256];
    red[t] = mean * mean;
    __syncthreads();
    for (int off = 128; off > 0; off >>= 1) {
        if (t < off) red[t] += red[t + off];
        __syncthreads();
    }
    const double nrm = sqrt(red[0]);
    const double pnv = mean / fmax(nrm, EPSD);
    pn64[(size_t)p * C + t] = pnv;

    // split-bf16 frag-order store: nt=p>>4, n-idx=p&15; ks=c>>5, quad=(c>>3)&3, j=c&7
    const float pnf = (float)pnv;
    const unsigned short phi = f2bf(pnf);
    const unsigned short plo = f2bf(pnf - bf2f(phi));
    const int nt = p >> 4, ks = t >> 5, lane = (((t >> 3) & 3) << 4) | (p & 15), j = t & 7;
    pB[FRAGOFF(nt, ks, 0, lane) + j] = phi;
    pB[FRAGOFF(nt, ks, 1, lane) + j] = plo;

    bool mybit = false;
    if (t < 64) {
        const int r = t >> 3, k = t & 7;
        mybit = sup_y[s * HW + (gy * 8 + r) * W + gx * 8 + k] > THRESH;
    }
    const unsigned long long bm = __ballot(mybit);   // wave 0 carries t=0..63
    if (t == 0) {
        valid[p] = (__popcll(bm) > 32) ? 1 : 0;      // mask_pooled > 0.5
        if (p == 0) *counter = 0;
    }
    if (t < 64) {
        const int i = p * 64 + t;
        out[OUT_GRID + i] = (sup_y[i] > THRESH) ? 1.0f : 0.0f;
    }
}

// ---------------------------------------------------------------------------
// Main: split-bf16 MFMA dists + fused softmax/argmax/pred.
//
// R9 (identical resubmit; R9 round died on container infra, never ran):
// HALF-CHUNK DOUBLE BUFFER at unchanged occupancy. R8 counters (87.5us):
// LDS-port busy 98k cyc (47%), MFMA 50k (24%), wall 210k -> ~112k cyc of
// collective stall. Structural source: barrier (b) drains the B stage
// (~400cyc L2) with only the ~150cyc convert between issue and drain, 2x per
// ks. Fix R1 couldn't afford (it paid occupancy for dbuf): split each ks
// chunk by proto-half -> 16 phases of 16 KiB; LDS = 2x16+1 = 33 KiB -> STILL
// 4 blocks/CU. Phase: issue stage(ph+1) into other buffer -> convert (even
// phases) -> compute 8 nt (16 ds_read + 24 MFMA, ~450+cyc) -> ONE barrier.
// The stage now has a full compute phase in flight before the vmcnt(0) drain.
// Same total reads/MFMA/barriers as R8; registers unchanged (h8/l8 live 2
// phases). Hazards: stage(ph+1) writes buf[!par] while compute reads
// buf[par]; buf[par] re-written only in phase ph+2, two barriers later.
// Spill tripwire: WRITE_SIZE > 20 MB. Null reading pre-committed: dist 87+-3
// with clean counters => structure is at equilibrium (cross-block overlap
// already covers the drain); remaining levers are fixed-overhead fusion or
// roofline.
// ---------------------------------------------------------------------------
__global__ __launch_bounds__(256, 4)
void dist_kernel(const float* __restrict__ qry, const unsigned short* __restrict__ pB,
                 const int* __restrict__ valid, float* __restrict__ out,
                 int* __restrict__ counter, int* __restrict__ suspects)
{
    __shared__ unsigned short ldsB[2][8 * 2 * 64 * 8];   // 2 x 16 KiB half-chunk buffers
    __shared__ int validLds[P];                          // 1 KiB

    const int t    = threadIdx.x;
    const int w    = t >> 6;      // wave -> pos-tile
    const int l    = t & 63;
    const int quad = l >> 4;
    const int m    = l & 15;

    const int b    = blockIdx.x >> 6;
    const int pos0 = (blockIdx.x & 63) * 64;

    validLds[t] = valid[t];

    // lane l covers pos = pos0 + w*16 + m, k = ks*32 + quad*8 + j
    const float* qp = qry + (size_t)b * C * HW + pos0 + w * 16 + m;

    floatx4 acc[16];
#pragma unroll
    for (int nt = 0; nt < 16; ++nt) acc[nt] = (floatx4){0.f, 0.f, 0.f, 0.f};

    // prologue: A loads for ks=0; stage phase 0 (ks=0, proto-half 0) into buf 0
    float vbuf[8];
#pragma unroll
    for (int j = 0; j < 8; ++j)
        vbuf[j] = qp[(size_t)(quad * 8 + j) * HW];
#pragma unroll
    for (int i = 0; i < 4; ++i) {
        const int c = w * 4 + i, ntl = c >> 1, h = c & 1;
        gl_lds16(pB + FRAGOFF(ntl, 0, h, 0) + l * 8,
                 &ldsB[0][(ntl * 2 + h) * 512]);
    }
    __syncthreads();   // phase-0 stage drained; validLds visible

    float ssq = 0.f;
    short8 h8, l8;     // A fragment for current ks (live across the 2 phases of a ks)
#pragma unroll
    for (int ph = 0; ph < 16; ++ph) {
        const int ks   = ph >> 1;
        const int half = ph & 1;    // proto-half of this phase
        const int par  = ph & 1;    // buffer parity (buf0 on even phases)

        // issue stage for phase ph+1 into the OTHER buffer (full compute phase
        // will be in flight before the end-of-phase barrier drains it)
        if (ph < 15) {
            const int ks2 = (ph + 1) >> 1, half2 = (ph + 1) & 1;
#pragma unroll
            for (int i = 0; i < 4; ++i) {
                const int c = w * 4 + i, ntl = c >> 1, h = c & 1;
                gl_lds16(pB + FRAGOFF(half2 * 8 + ntl, ks2, h, 0) + l * 8,
                         &ldsB[(ph + 1) & 1][(ntl * 2 + h) * 512]);
            }
        }
        // even phase: convert A(ks) from vbuf, then prefetch A(ks+1)
        if (half == 0) {
#pragma unroll
            for (int j = 0; j < 8; ++j) {
                const float v = vbuf[j];
                ssq = fmaf(v, v, ssq);
                const unsigned short hi = f2bf(v);
                h8[j] = (short)hi;
                l8[j] = (short)f2bf(v - bf2f(hi));
            }
            if (ks < 7) {
#pragma unroll
                for (int j = 0; j < 8; ++j)
                    vbuf[j] = qp[(size_t)((ks + 1) * 32 + quad * 8 + j) * HW];
            }
        }
        // compute phase ph: 8 proto-tiles from buf[par]
#pragma unroll
        for (int ntl = 0; ntl < 8; ++ntl) {
            const short8 bh = *(const short8*)&ldsB[par][((ntl * 2 + 0) * 64 + l) * 8];
            const short8 bl = *(const short8*)&ldsB[par][((ntl * 2 + 1) * 64 + l) * 8];
            const int nt = half * 8 + ntl;
            acc[nt] = __builtin_amdgcn_mfma_f32_16x16x32_bf16(h8, bh, acc[nt], 0, 0, 0);
            acc[nt] = __builtin_amdgcn_mfma_f32_16x16x32_bf16(h8, bl, acc[nt], 0, 0, 0);
            acc[nt] = __builtin_amdgcn_mfma_f32_16x16x32_bf16(l8, bh, acc[nt], 0, 0, 0);
        }
        __syncthreads();   // drains own stage(ph+1) + ds_reads; orders buffer reuse
    }

    // ||q||^2 for pos w*16+m: sum the 4 quads (lanes differing in bits 4,5)
    ssq += __shfl_xor(ssq, 16);
    ssq += __shfl_xor(ssq, 32);
    const float scalev = SCALE / fmaxf(sqrtf(ssq), EPSF);

    // ---- epilogue (wave-local). C/D: proto = nt*16 + m, pos-in-tile = quad*4 + r ----
    int vbits = 0;
#pragma unroll
    for (int nt = 0; nt < 16; ++nt) vbits |= validLds[nt * 16 + m] << nt;

    float scr[4];
#pragma unroll
    for (int r = 0; r < 4; ++r) scr[r] = __shfl(scalev, quad * 4 + r);   // lane quad*4+r holds pos w*16+quad*4+r
#pragma unroll
    for (int nt = 0; nt < 16; ++nt)
#pragma unroll
        for (int r = 0; r < 4; ++r) acc[nt][r] *= scr[r];   // positive factor: ordering-safe

#pragma unroll
    for (int r = 0; r < 4; ++r) {
        // pass 1: max / argmax (first occurrence) / 2nd-max
        float m1 = -INFINITY, m2 = -INFINITY; int id = 0x7fffffff;
#pragma unroll
        for (int nt = 0; nt < 16; ++nt) {
            if (vbits & (1 << nt)) {
                const float d = acc[nt][r];
                if (d > m1)      { m2 = m1; m1 = d; id = nt * 16 + m; }
                else if (d > m2) { m2 = d; }
            }
        }
#pragma unroll
        for (int sh = 1; sh < 16; sh <<= 1) {   // reduce over m (protos), within quad
            const float om1 = __shfl_xor(m1, sh);
            const float om2 = __shfl_xor(m2, sh);
            const int   oid = __shfl_xor(id, sh);
            if (om1 > m1) { m2 = fmaxf(m1, om2); m1 = om1; id = oid; }
            else { if (om1 == m1 && oid < id) id = oid; m2 = fmaxf(m2, om1); }
        }
        const int posg = b * HW + pos0 + w * 16 + quad * 4 + r;
        if (m == 0) {
            out[OUT_ASSIGN + posg] = (float)id;
            if (m1 - m2 < GAP_THRESH) {          // near-tie -> exact fp64 recheck
                const int slot = atomicAdd(counter, 1);
                if (slot < MAXSUS) suspects[slot] = posg;
            }
        }
        // pass 2: softmax denominator and weighted sum (all lanes hold m1)
        float se = 0.f, sw = 0.f;
#pragma unroll
        for (int nt = 0; nt < 16; ++nt) {
            if (vbits & (1 << nt)) {
                const float d = acc[nt][r];
                const float e = __expf(d - m1);
                se += e; sw = fmaf(e, d, sw);
            }
        }
#pragma unroll
        for (int sh = 1; sh < 16; sh <<= 1) {
            se += __shfl_xor(se, sh);
            sw += __shfl_xor(sw, sh);
        }
        if (m == 0) out[posg] = sw / se;
    }
}

// ---------------------------------------------------------------------------
// Recheck (R8 structure, unchanged): one wave per suspect, grid-stride,
// uniform trip counts; lane l owns protos {l, l+64, l+128, l+192}; fp64 4-way
// split chains; first-occurrence tie-break.
// ---------------------------------------------------------------------------
__global__ __launch_bounds__(256)
void recheck_kernel(const float* __restrict__ qry, const double* __restrict__ pn64,
                    const int* __restrict__ valid, const int* __restrict__ counter,
                    const int* __restrict__ suspects, float* __restrict__ out)
{
    __shared__ float qsh[4][256];
    const int t = threadIdx.x;
    const int w = t >> 6, l = t & 63;
    int n = *counter; if (n > MAXSUS) n = MAXSUS;
    const int nb = (n + 3) >> 2;            // 4 suspects per block-iteration

    for (int batch = blockIdx.x; batch < nb; batch += gridDim.x) {
        const int si = batch * 4 + w;       // this wave's suspect
        const bool active = si < n;
        int pos = 0;
        if (active) {
            pos = suspects[si];
            // load q column: lane l loads c = l + 64*k into this wave's LDS row
#pragma unroll
            for (int k = 0; k < 4; ++k) {
                const int c = l + 64 * k;
                qsh[w][c] = qry[(size_t)(pos >> 12) * (C * HW) + (size_t)c * HW + (pos & (HW - 1))];
            }
        }
        __syncthreads();                    // qsh visible (uniform across block)
        if (active) {
            double best = -INFINITY; int bid = 0x7fffffff;
#pragma unroll
            for (int k = 0; k < 4; ++k) {
                const int p = l + 64 * k;   // increasing id order within lane
                if (valid[p]) {
                    const double* pr = pn64 + (size_t)p * C;
                    double a0 = 0.0, a1 = 0.0, a2 = 0.0, a3 = 0.0;
#pragma unroll 4
                    for (int c = 0; c < C; c += 4) {
                        a0 = fma((double)qsh[w][c + 0], pr[c + 0], a0);
                        a1 = fma((double)qsh[w][c + 1], pr[c + 1], a1);
                        a2 = fma((double)qsh[w][c + 2], pr[c + 2], a2);
                        a3 = fma((double)qsh[w][c + 3], pr[c + 3], a3);
                    }
                    const double d = (a0 + a1) + (a2 + a3);
                    if (d > best) { best = d; bid = p; }   // strict > keeps smallest id on ties
                }
            }
            // wave-wide reduce: max, smallest-id tie-break (first occurrence)
#pragma unroll
            for (int sh = 1; sh < 64; sh <<= 1) {
                const double od = __shfl_xor(best, sh);
                const int    oi = __shfl_xor(bid, sh);
                if (od > best || (od == best && oi < bid)) { best = od; bid = oi; }
            }
            if (l == 0) out[OUT_ASSIGN + pos] = (float)bid;
        }
        __syncthreads();                    // guard qsh overwrite next iteration
    }
}

// ---------------------------------------------------------------------------
extern "C" void kernel_launch(void* const* d_in, const int* in_sizes, int n_in,
                              void* d_out, int out_size, void* d_ws, size_t ws_size,
                              hipStream_t stream)
{
    const float* qry   = (const float*)d_in[0];
    const float* sup_x = (const float*)d_in[1];
    const float* sup_y = (const float*)d_in[2];
    float* out = (float*)d_out;
    char*  ws  = (char*)d_ws;

    // ws layout (~1.03 MiB total)
    unsigned short* pB       = (unsigned short*)(ws);            // 256 KiB frag-order split-bf16 protos
    double*         pn64     = (double*)(ws + 256 * 1024);       // 512 KiB
    int*            valid    = (int*)(ws + 768 * 1024);          // 1 KiB
    int*            counter  = (int*)(ws + 768 * 1024 + 1024);   // 4 B
    int*            suspects = (int*)(ws + 768 * 1024 + 2048);   // 256 KiB

    prep_kernel<<<dim3(P), dim3(256), 0, stream>>>(sup_x, sup_y, out, pB, pn64, valid, counter);
    dist_kernel<<<dim3(BQ * (HW / 64)), dim3(256), 0, stream>>>(qry, pB, valid, out, counter, suspects);
    recheck_kernel<<<dim3(1024), dim3(256), 0, stream>>>(qry, pn64, valid, counter, suspects, out);
}

// Round 11
// 282.211 us; speedup vs baseline: 1.6198x; 1.6198x over previous
//
#include <hip/hip_runtime.h>
#include <math.h>

// Problem constants
constexpr int BQ = 32;       // query batch
constexpr int C  = 256;      // channels
constexpr int HW = 4096;     // 64*64
constexpr int W  = 64;
constexpr int P  = 256;      // protos (4 * 8 * 8)
constexpr float THRESH = 0.95f;
constexpr float SCALE  = 20.0f;
constexpr float EPSF   = 1e-4f;
constexpr double EPSD  = 1e-4;
constexpr float GAP_THRESH = 2e-3f;   // split-bf16 dist err ~5e-4 -> 4x margin
constexpr int MAXSUS = 65536;

// d_out layout: pred [0, 131072) | debug_assign [131072, 262144) | proto_grid [262144, 278528)
constexpr int OUT_ASSIGN = BQ * HW;
constexpr int OUT_GRID   = 2 * BQ * HW;

typedef __attribute__((ext_vector_type(8))) short short8;
typedef __attribute__((ext_vector_type(4))) float floatx4;

static __device__ __forceinline__ unsigned short f2bf(float x) {
    unsigned u = __float_as_uint(x);
    u += 0x7FFFu + ((u >> 16) & 1u);     // round-to-nearest-even (no NaN inputs)
    return (unsigned short)(u >> 16);
}
static __device__ __forceinline__ float bf2f(unsigned short h) {
    return __uint_as_float(((unsigned)h) << 16);
}

// Fragment-order offset (ushort units): [tile][ks][h][lane][j], lane = quad*16 + idx,
// element j of lane <-> k = ks*32 + quad*8 + j. A and B use the IDENTICAL map, so
// any k-permutation cancels in the MFMA contraction.
#define FRAGOFF(tile, ks, h, lane) (((((tile) * 8 + (ks)) * 2 + (h)) * 64 + (lane)) * 8)

// async global->LDS, 16 B/lane; LDS dest = wave-uniform base + lane*16
static __device__ __forceinline__ void gl_lds16(const unsigned short* gp, unsigned short* lp) {
    __builtin_amdgcn_global_load_lds(
        (const __attribute__((address_space(1))) unsigned int*)gp,
        (__attribute__((address_space(3))) unsigned int*)lp, 16, 0, 0);
}

// ---------------------------------------------------------------------------
// Prep: pooled protos (fp64 normalize) -> split-bf16 frag-order pB + fp64 pn64,
// valid flags, proto_grid output, zero suspect counter. Block=proto, thread=channel.
// ---------------------------------------------------------------------------
__global__ __launch_bounds__(256)
void prep_kernel(const float* __restrict__ sup_x, const float* __restrict__ sup_y,
                 float* __restrict__ out, unsigned short* __restrict__ pB,
                 double* __restrict__ pn64, int* __restrict__ valid,
                 int* __restrict__ counter)
{
    const int p = blockIdx.x;     // proto index = s*64 + gy*8 + gx
    const int t = threadIdx.x;    // channel
    const int s = p >> 6, gy = (p >> 3) & 7, gx = p & 7;

    const float* base = sup_x + ((size_t)(s * C + t)) * HW + (gy * 8) * W + gx * 8;
    double sum = 0.0;
#pragma unroll
    for (int r = 0; r < 8; ++r) {
        const float4 a  = *(const float4*)(base + r * W);
        const float4 bq = *(const float4*)(base + r * W + 4);
        sum += (double)a.x;  sum += (double)a.y;  sum += (double)a.z;  sum += (double)a.w;
        sum += (double)bq.x; sum += (double)bq.y; sum += (double)bq.z; sum += (double)bq.w;
    }
    const double mean = sum * (1.0 / 64.0);

    __shared__ double red[256];
    red[t] = mean * mean;
    __syncthreads();
    for (int off = 128; off > 0; off >>= 1) {
        if (t < off) red[t] += red[t + off];
        __syncthreads();
    }
    const double nrm = sqrt(red[0]);
    const double pnv = mean / fmax(nrm, EPSD);
    pn64[(size_t)p * C + t] = pnv;

    // split-bf16 frag-order store: nt=p>>4, n-idx=p&15; ks=c>>5, quad=(c>>3)&3, j=c&7
    const float pnf = (float)pnv;
    const unsigned short phi = f2bf(pnf);
    const unsigned short plo = f2bf(pnf - bf2f(phi));
    const int nt = p >> 4, ks = t >> 5, lane = (((t >> 3) & 3) << 4) | (p & 15), j = t & 7;
    pB[FRAGOFF(nt, ks, 0, lane) + j] = phi;
    pB[FRAGOFF(nt, ks, 1, lane) + j] = plo;

    bool mybit = false;
    if (t < 64) {
        const int r = t >> 3, k = t & 7;
        mybit = sup_y[s * HW + (gy * 8 + r) * W + gx * 8 + k] > THRESH;
    }
    const unsigned long long bm = __ballot(mybit);   // wave 0 carries t=0..63
    if (t == 0) {
        valid[p] = (__popcll(bm) > 32) ? 1 : 0;      // mask_pooled > 0.5
        if (p == 0) *counter = 0;
    }
    if (t < 64) {
        const int i = p * 64 + t;
        out[OUT_GRID + i] = (sup_y[i] > THRESH) ? 1.0f : 0.0f;
    }
}

// ---------------------------------------------------------------------------
// Main: split-bf16 MFMA dists + fused softmax/argmax/pred.
//
// R11: half-chunk double buffer, SPILL-PROOF SHAPE. R10's 562 MB scratch came
// from the single 16-phase loop not fully unrolling -> runtime `half` ->
// acc[half*8+ntl] runtime-indexed -> whole accumulator array in scratch
// (rule: runtime-indexed ext_vector arrays go to localMem). Fix: keep R8's
// proven 8-iteration ks-loop shape; write the two half-phases as EXPLICIT
// code so every acc index is a literal. Per ks:
//   stage(ks,h1)->buf1 ; convert ; prefetch A(ks+1) ;
//   compute acc[0..8) from buf0 ; BARRIER ;
//   stage(ks+1,h0)->buf0 ; compute acc[8..16) from buf1 ; BARRIER.
// Every staging stream (B halves AND A prefetch) now has a full ~400+cyc
// compute phase in flight before the barrier's vmcnt(0) drain (R8: ~150cyc
// convert for B, ~0 for A). Registers == R8 (vbuf 8 + h8/l8 + 64 AGPR);
// LDS 2x16+1 = 33 KiB -> 4 blocks/CU; barrier count unchanged.
// Hazards: stage->buf1 in phase A overlaps reads of buf0 (disjoint); the
// phase-A barrier orders phase-B's overwrite of buf0 after all buf0 reads;
// the phase-B barrier orders next-ks overwrite of buf1 after buf1 reads.
// Tripwires (pre-committed): WRITE_SIZE>20MB -> revert to R8 permanently;
// clean null (87+-3, VGPR 64, WRITE ~3MB) -> structure at equilibrium.
// ---------------------------------------------------------------------------
__global__ __launch_bounds__(256, 4)
void dist_kernel(const float* __restrict__ qry, const unsigned short* __restrict__ pB,
                 const int* __restrict__ valid, float* __restrict__ out,
                 int* __restrict__ counter, int* __restrict__ suspects)
{
    __shared__ unsigned short ldsB0[8 * 2 * 64 * 8];   // 16 KiB half-chunk buffer 0
    __shared__ unsigned short ldsB1[8 * 2 * 64 * 8];   // 16 KiB half-chunk buffer 1
    __shared__ int validLds[P];                        // 1 KiB

    const int t    = threadIdx.x;
    const int w    = t >> 6;      // wave -> pos-tile
    const int l    = t & 63;
    const int quad = l >> 4;
    const int m    = l & 15;

    const int b    = blockIdx.x >> 6;
    const int pos0 = (blockIdx.x & 63) * 64;

    validLds[t] = valid[t];

    // lane l covers pos = pos0 + w*16 + m, k = ks*32 + quad*8 + j
    const float* qp = qry + (size_t)b * C * HW + pos0 + w * 16 + m;

    floatx4 acc[16];
#pragma unroll
    for (int nt = 0; nt < 16; ++nt) acc[nt] = (floatx4){0.f, 0.f, 0.f, 0.f};

    // prologue: A loads for ks=0; stage (ks=0, proto-half 0) into buf0
    float vbuf[8];
#pragma unroll
    for (int j = 0; j < 8; ++j)
        vbuf[j] = qp[(size_t)(quad * 8 + j) * HW];
#pragma unroll
    for (int i = 0; i < 4; ++i) {
        const int c = w * 4 + i, ntl = c >> 1, h = c & 1;
        gl_lds16(pB + FRAGOFF(ntl, 0, h, 0) + l * 8,
                 &ldsB0[(ntl * 2 + h) * 512]);
    }
    __syncthreads();   // prologue stage drained; validLds visible

    float ssq = 0.f;
#pragma unroll
    for (int ks = 0; ks < 8; ++ks) {
        // ---- phase A: stage (ks, half1)->buf1; convert+prefetch; compute half0 from buf0
#pragma unroll
        for (int i = 0; i < 4; ++i) {
            const int c = w * 4 + i, ntl = c >> 1, h = c & 1;
            gl_lds16(pB + FRAGOFF(8 + ntl, ks, h, 0) + l * 8,
                     &ldsB1[(ntl * 2 + h) * 512]);
        }
        short8 h8, l8;
#pragma unroll
        for (int j = 0; j < 8; ++j) {
            const float v = vbuf[j];
            ssq = fmaf(v, v, ssq);
            const unsigned short hi = f2bf(v);
            h8[j] = (short)hi;
            l8[j] = (short)f2bf(v - bf2f(hi));
        }
        if (ks < 7) {
#pragma unroll
            for (int j = 0; j < 8; ++j)
                vbuf[j] = qp[(size_t)((ks + 1) * 32 + quad * 8 + j) * HW];
        }
#pragma unroll
        for (int ntl = 0; ntl < 8; ++ntl) {
            const short8 bh = *(const short8*)&ldsB0[((ntl * 2 + 0) * 64 + l) * 8];
            const short8 bl = *(const short8*)&ldsB0[((ntl * 2 + 1) * 64 + l) * 8];
            acc[ntl] = __builtin_amdgcn_mfma_f32_16x16x32_bf16(h8, bh, acc[ntl], 0, 0, 0);
            acc[ntl] = __builtin_amdgcn_mfma_f32_16x16x32_bf16(h8, bl, acc[ntl], 0, 0, 0);
            acc[ntl] = __builtin_amdgcn_mfma_f32_16x16x32_bf16(l8, bh, acc[ntl], 0, 0, 0);
        }
        __syncthreads();   // drains stage->buf1 + buf0 reads; orders buf0 overwrite below

        // ---- phase B: stage (ks+1, half0)->buf0; compute half1 from buf1
        if (ks < 7) {
#pragma unroll
            for (int i = 0; i < 4; ++i) {
                const int c = w * 4 + i, ntl = c >> 1, h = c & 1;
                gl_lds16(pB + FRAGOFF(ntl, ks + 1, h, 0) + l * 8,
                         &ldsB0[(ntl * 2 + h) * 512]);
            }
        }
#pragma unroll
        for (int ntl = 0; ntl < 8; ++ntl) {
            const short8 bh = *(const short8*)&ldsB1[((ntl * 2 + 0) * 64 + l) * 8];
            const short8 bl = *(const short8*)&ldsB1[((ntl * 2 + 1) * 64 + l) * 8];
            acc[8 + ntl] = __builtin_amdgcn_mfma_f32_16x16x32_bf16(h8, bh, acc[8 + ntl], 0, 0, 0);
            acc[8 + ntl] = __builtin_amdgcn_mfma_f32_16x16x32_bf16(h8, bl, acc[8 + ntl], 0, 0, 0);
            acc[8 + ntl] = __builtin_amdgcn_mfma_f32_16x16x32_bf16(l8, bh, acc[8 + ntl], 0, 0, 0);
        }
        if (ks < 7) __syncthreads();   // drains stage->buf0 + buf1 reads; orders buf1 overwrite
    }

    // ||q||^2 for pos w*16+m: sum the 4 quads (lanes differing in bits 4,5)
    ssq += __shfl_xor(ssq, 16);
    ssq += __shfl_xor(ssq, 32);
    const float scalev = SCALE / fmaxf(sqrtf(ssq), EPSF);

    // ---- epilogue (wave-local). C/D: proto = nt*16 + m, pos-in-tile = quad*4 + r ----
    int vbits = 0;
#pragma unroll
    for (int nt = 0; nt < 16; ++nt) vbits |= validLds[nt * 16 + m] << nt;

    float scr[4];
#pragma unroll
    for (int r = 0; r < 4; ++r) scr[r] = __shfl(scalev, quad * 4 + r);   // lane quad*4+r holds pos w*16+quad*4+r
#pragma unroll
    for (int nt = 0; nt < 16; ++nt)
#pragma unroll
        for (int r = 0; r < 4; ++r) acc[nt][r] *= scr[r];   // positive factor: ordering-safe

#pragma unroll
    for (int r = 0; r < 4; ++r) {
        // pass 1: max / argmax (first occurrence) / 2nd-max
        float m1 = -INFINITY, m2 = -INFINITY; int id = 0x7fffffff;
#pragma unroll
        for (int nt = 0; nt < 16; ++nt) {
            if (vbits & (1 << nt)) {
                const float d = acc[nt][r];
                if (d > m1)      { m2 = m1; m1 = d; id = nt * 16 + m; }
                else if (d > m2) { m2 = d; }
            }
        }
#pragma unroll
        for (int sh = 1; sh < 16; sh <<= 1) {   // reduce over m (protos), within quad
            const float om1 = __shfl_xor(m1, sh);
            const float om2 = __shfl_xor(m2, sh);
            const int   oid = __shfl_xor(id, sh);
            if (om1 > m1) { m2 = fmaxf(m1, om2); m1 = om1; id = oid; }
            else { if (om1 == m1 && oid < id) id = oid; m2 = fmaxf(m2, om1); }
        }
        const int posg = b * HW + pos0 + w * 16 + quad * 4 + r;
        if (m == 0) {
            out[OUT_ASSIGN + posg] = (float)id;
            if (m1 - m2 < GAP_THRESH) {          // near-tie -> exact fp64 recheck
                const int slot = atomicAdd(counter, 1);
                if (slot < MAXSUS) suspects[slot] = posg;
            }
        }
        // pass 2: softmax denominator and weighted sum (all lanes hold m1)
        float se = 0.f, sw = 0.f;
#pragma unroll
        for (int nt = 0; nt < 16; ++nt) {
            if (vbits & (1 << nt)) {
                const float d = acc[nt][r];
                const float e = __expf(d - m1);
                se += e; sw = fmaf(e, d, sw);
            }
        }
#pragma unroll
        for (int sh = 1; sh < 16; sh <<= 1) {
            se += __shfl_xor(se, sh);
            sw += __shfl_xor(sw, sh);
        }
        if (m == 0) out[posg] = sw / se;
    }
}

// ---------------------------------------------------------------------------
// Recheck (R8 structure, unchanged): one wave per suspect, grid-stride,
// uniform trip counts; lane l owns protos {l, l+64, l+128, l+192}; fp64 4-way
// split chains; first-occurrence tie-break.
// ---------------------------------------------------------------------------
__global__ __launch_bounds__(256)
void recheck_kernel(const float* __restrict__ qry, const double* __restrict__ pn64,
                    const int* __restrict__ valid, const int* __restrict__ counter,
                    const int* __restrict__ suspects, float* __restrict__ out)
{
    __shared__ float qsh[4][256];
    const int t = threadIdx.x;
    const int w = t >> 6, l = t & 63;
    int n = *counter; if (n > MAXSUS) n = MAXSUS;
    const int nb = (n + 3) >> 2;            // 4 suspects per block-iteration

    for (int batch = blockIdx.x; batch < nb; batch += gridDim.x) {
        const int si = batch * 4 + w;       // this wave's suspect
        const bool active = si < n;
        int pos = 0;
        if (active) {
            pos = suspects[si];
            // load q column: lane l loads c = l + 64*k into this wave's LDS row
#pragma unroll
            for (int k = 0; k < 4; ++k) {
                const int c = l + 64 * k;
                qsh[w][c] = qry[(size_t)(pos >> 12) * (C * HW) + (size_t)c * HW + (pos & (HW - 1))];
            }
        }
        __syncthreads();                    // qsh visible (uniform across block)
        if (active) {
            double best = -INFINITY; int bid = 0x7fffffff;
#pragma unroll
            for (int k = 0; k < 4; ++k) {
                const int p = l + 64 * k;   // increasing id order within lane
                if (valid[p]) {
                    const double* pr = pn64 + (size_t)p * C;
                    double a0 = 0.0, a1 = 0.0, a2 = 0.0, a3 = 0.0;
#pragma unroll 4
                    for (int c = 0; c < C; c += 4) {
                        a0 = fma((double)qsh[w][c + 0], pr[c + 0], a0);
                        a1 = fma((double)qsh[w][c + 1], pr[c + 1], a1);
                        a2 = fma((double)qsh[w][c + 2], pr[c + 2], a2);
                        a3 = fma((double)qsh[w][c + 3], pr[c + 3], a3);
                    }
                    const double d = (a0 + a1) + (a2 + a3);
                    if (d > best) { best = d; bid = p; }   // strict > keeps smallest id on ties
                }
            }
            // wave-wide reduce: max, smallest-id tie-break (first occurrence)
#pragma unroll
            for (int sh = 1; sh < 64; sh <<= 1) {
                const double od = __shfl_xor(best, sh);
                const int    oi = __shfl_xor(bid, sh);
                if (od > best || (od == best && oi < bid)) { best = od; bid = oi; }
            }
            if (l == 0) out[OUT_ASSIGN + pos] = (float)bid;
        }
        __syncthreads();                    // guard qsh overwrite next iteration
    }
}

// ---------------------------------------------------------------------------
extern "C" void kernel_launch(void* const* d_in, const int* in_sizes, int n_in,
                              void* d_out, int out_size, void* d_ws, size_t ws_size,
                              hipStream_t stream)
{
    const float* qry   = (const float*)d_in[0];
    const float* sup_x = (const float*)d_in[1];
    const float* sup_y = (const float*)d_in[2];
    float* out = (float*)d_out;
    char*  ws  = (char*)d_ws;

    // ws layout (~1.03 MiB total)
    unsigned short* pB       = (unsigned short*)(ws);            // 256 KiB frag-order split-bf16 protos
    double*         pn64     = (double*)(ws + 256 * 1024);       // 512 KiB
    int*            valid    = (int*)(ws + 768 * 1024);          // 1 KiB
    int*            counter  = (int*)(ws + 768 * 1024 + 1024);   // 4 B
    int*            suspects = (int*)(ws + 768 * 1024 + 2048);   // 256 KiB

    prep_kernel<<<dim3(P), dim3(256), 0, stream>>>(sup_x, sup_y, out, pB, pn64, valid, counter);
    dist_kernel<<<dim3(BQ * (HW / 64)), dim3(256), 0, stream>>>(qry, pB, valid, out, counter, suspects);
    recheck_kernel<<<dim3(1024), dim3(256), 0, stream>>>(qry, pn64, valid, counter, suspects, out);
}

// Round 12
// 273.747 us; speedup vs baseline: 1.6699x; 1.0309x over previous
//
#include <hip/hip_runtime.h>
#include <math.h>

// Problem constants
constexpr int BQ = 32;       // query batch
constexpr int C  = 256;      // channels
constexpr int HW = 4096;     // 64*64
constexpr int W  = 64;
constexpr int P  = 256;      // protos (4 * 8 * 8)
constexpr float THRESH = 0.95f;
constexpr float SCALE  = 20.0f;
constexpr float EPSF   = 1e-4f;
constexpr double EPSD  = 1e-4;
constexpr float GAP_THRESH = 2e-3f;   // split-bf16 dist err ~5e-4 -> 4x margin
constexpr int MAXSUS = 65536;

// d_out layout: pred [0, 131072) | debug_assign [131072, 262144) | proto_grid [262144, 278528)
constexpr int OUT_ASSIGN = BQ * HW;
constexpr int OUT_GRID   = 2 * BQ * HW;

typedef __attribute__((ext_vector_type(8))) short short8;
typedef __attribute__((ext_vector_type(4))) float floatx4;

static __device__ __forceinline__ unsigned short f2bf(float x) {
    unsigned u = __float_as_uint(x);
    u += 0x7FFFu + ((u >> 16) & 1u);     // round-to-nearest-even (no NaN inputs)
    return (unsigned short)(u >> 16);
}
static __device__ __forceinline__ float bf2f(unsigned short h) {
    return __uint_as_float(((unsigned)h) << 16);
}

// Fragment-order offset (ushort units): [tile][ks][h][lane][j], lane = quad*16 + idx,
// element j of lane <-> k = ks*32 + quad*8 + j. A and B use the IDENTICAL map, so
// any k-permutation cancels in the MFMA contraction.
#define FRAGOFF(tile, ks, h, lane) (((((tile) * 8 + (ks)) * 2 + (h)) * 64 + (lane)) * 8)

// async global->LDS, 16 B/lane; LDS dest = wave-uniform base + lane*16
static __device__ __forceinline__ void gl_lds16(const unsigned short* gp, unsigned short* lp) {
    __builtin_amdgcn_global_load_lds(
        (const __attribute__((address_space(1))) unsigned int*)gp,
        (__attribute__((address_space(3))) unsigned int*)lp, 16, 0, 0);
}

// ---------------------------------------------------------------------------
// Prep: pooled protos (fp64 normalize) -> split-bf16 frag-order pB + fp64 pn64,
// valid flags, proto_grid output, zero suspect counter. Block=proto, thread=channel.
// ---------------------------------------------------------------------------
__global__ __launch_bounds__(256)
void prep_kernel(const float* __restrict__ sup_x, const float* __restrict__ sup_y,
                 float* __restrict__ out, unsigned short* __restrict__ pB,
                 double* __restrict__ pn64, int* __restrict__ valid,
                 int* __restrict__ counter)
{
    const int p = blockIdx.x;     // proto index = s*64 + gy*8 + gx
    const int t = threadIdx.x;    // channel
    const int s = p >> 6, gy = (p >> 3) & 7, gx = p & 7;

    const float* base = sup_x + ((size_t)(s * C + t)) * HW + (gy * 8) * W + gx * 8;
    double sum = 0.0;
#pragma unroll
    for (int r = 0; r < 8; ++r) {
        const float4 a  = *(const float4*)(base + r * W);
        const float4 bq = *(const float4*)(base + r * W + 4);
        sum += (double)a.x;  sum += (double)a.y;  sum += (double)a.z;  sum += (double)a.w;
        sum += (double)bq.x; sum += (double)bq.y; sum += (double)bq.z; sum += (double)bq.w;
    }
    const double mean = sum * (1.0 / 64.0);

    __shared__ double red[256];
    red[t] = mean * mean;
    __syncthreads();
    for (int off = 128; off > 0; off >>= 1) {
        if (t < off) red[t] += red[t + off];
        __syncthreads();
    }
    const double nrm = sqrt(red[0]);
    const double pnv = mean / fmax(nrm, EPSD);
    pn64[(size_t)p * C + t] = pnv;

    // split-bf16 frag-order store: nt=p>>4, n-idx=p&15; ks=c>>5, quad=(c>>3)&3, j=c&7
    const float pnf = (float)pnv;
    const unsigned short phi = f2bf(pnf);
    const unsigned short plo = f2bf(pnf - bf2f(phi));
    const int nt = p >> 4, ks = t >> 5, lane = (((t >> 3) & 3) << 4) | (p & 15), j = t & 7;
    pB[FRAGOFF(nt, ks, 0, lane) + j] = phi;
    pB[FRAGOFF(nt, ks, 1, lane) + j] = plo;

    bool mybit = false;
    if (t < 64) {
        const int r = t >> 3, k = t & 7;
        mybit = sup_y[s * HW + (gy * 8 + r) * W + gx * 8 + k] > THRESH;
    }
    const unsigned long long bm = __ballot(mybit);   // wave 0 carries t=0..63
    if (t == 0) {
        valid[p] = (__popcll(bm) > 32) ? 1 : 0;      // mask_pooled > 0.5
        if (p == 0) *counter = 0;
    }
    if (t < 64) {
        const int i = p * 64 + t;
        out[OUT_GRID + i] = (sup_y[i] > THRESH) ? 1.0f : 0.0f;
    }
}

// ---------------------------------------------------------------------------
// Main: split-bf16 MFMA dists + fused softmax/argmax/pred.
// R12 = PERMANENT REVERT to the R8/R2 kernel (measured 87.5 us, VGPR 64,
// Occ 37%, MfmaUtil 24%, WRITE 3.1 MB, conflicts 0). This point is the
// register-budget equilibrium: 64 arch + 64 AGPR acc = exactly the 128-reg
// (256,4) budget. Session ledger of dist restructures, all regressions:
//   R1  dbuf @2 blocks/CU           135 us (occupancy loss)
//   R3  counted vmcnt + sched pins  108 us (spill: pins + reg cap)
//   R4  2x B-reuse @2 blocks/CU     100 us (occupancy loss + mild spill)
//   R5-7 32x32x16 shape             197 us (A-path needs >64 arch -> spill)
//   R9-11 half-chunk double buffer   96 us (2 staging streams >64 arch -> spill)
// Mechanisms are exhaustive at this tile shape: any schedule holding more
// live state than {vbuf8, h8/l8, addresses} spills; any occupancy sacrifice
// costs more than the stall it hides. Remaining gap to the ~48us LDS-port
// floor is structural at HIP source level (barrier-drain + lockstep waves).
// Block = 64 positions (4 waves); wave w owns pos-tile w (16 pos) x ALL 256
// protos. Per-ks A streaming: 8-float prefetch buffer + 8-VGPR fragment;
// convert VALU fills the B-stage drain window.
// ---------------------------------------------------------------------------
__global__ __launch_bounds__(256, 4)
void dist_kernel(const float* __restrict__ qry, const unsigned short* __restrict__ pB,
                 const int* __restrict__ valid, float* __restrict__ out,
                 int* __restrict__ counter, int* __restrict__ suspects)
{
    __shared__ unsigned short ldsB[16 * 2 * 64 * 8];   // 32 KiB: [nt][h][lane][j]
    __shared__ int validLds[P];                        // 1 KiB

    const int t    = threadIdx.x;
    const int w    = t >> 6;      // wave -> pos-tile
    const int l    = t & 63;
    const int quad = l >> 4;
    const int m    = l & 15;

    const int b    = blockIdx.x >> 6;
    const int pos0 = (blockIdx.x & 63) * 64;

    validLds[t] = valid[t];

    // lane l covers pos = pos0 + w*16 + m, k = ks*32 + quad*8 + j
    const float* qp = qry + (size_t)b * C * HW + pos0 + w * 16 + m;

    floatx4 acc[16];
#pragma unroll
    for (int nt = 0; nt < 16; ++nt) acc[nt] = (floatx4){0.f, 0.f, 0.f, 0.f};

    // prologue: issue A loads for ks=0 (drained by the first barrier)
    float vbuf[8];
#pragma unroll
    for (int j = 0; j < 8; ++j)
        vbuf[j] = qp[(size_t)(quad * 8 + j) * HW];

    float ssq = 0.f;
#pragma unroll
    for (int ks = 0; ks < 8; ++ks) {
        __syncthreads();                 // (a) prev chunk's LDS readers done; A(ks) drained
        // stage B(ks): 32 chunks of 1 KiB; wave w stages chunks w*8..w*8+7
#pragma unroll
        for (int i = 0; i < 8; ++i) {
            const int idx = w * 8 + i, nt = idx >> 1, h = idx & 1;
            gl_lds16(pB + FRAGOFF(nt, ks, h, 0) + l * 8,
                     &ldsB[(nt * 2 + h) * 512]);
        }
        // convert A(ks) from vbuf (VALU work overlaps the B-stage flight)
        short8 h8, l8;
#pragma unroll
        for (int j = 0; j < 8; ++j) {
            const float v = vbuf[j];
            ssq = fmaf(v, v, ssq);
            const unsigned short hi = f2bf(v);
            h8[j] = (short)hi;
            l8[j] = (short)f2bf(v - bf2f(hi));
        }
        // prefetch A(ks+1) (drained at barrier (b) below; ready next iteration)
        if (ks < 7) {
#pragma unroll
            for (int j = 0; j < 8; ++j)
                vbuf[j] = qp[(size_t)((ks + 1) * 32 + quad * 8 + j) * HW];
        }
        __syncthreads();                 // (b) vmcnt drained -> B(ks) visible
#pragma unroll
        for (int nt = 0; nt < 16; ++nt) {
            const short8 bh = *(const short8*)&ldsB[((nt * 2 + 0) * 64 + l) * 8];
            const short8 bl = *(const short8*)&ldsB[((nt * 2 + 1) * 64 + l) * 8];
            acc[nt] = __builtin_amdgcn_mfma_f32_16x16x32_bf16(h8, bh, acc[nt], 0, 0, 0);
            acc[nt] = __builtin_amdgcn_mfma_f32_16x16x32_bf16(h8, bl, acc[nt], 0, 0, 0);
            acc[nt] = __builtin_amdgcn_mfma_f32_16x16x32_bf16(l8, bh, acc[nt], 0, 0, 0);
        }
    }

    // ||q||^2 for pos w*16+m: sum the 4 quads (lanes differing in bits 4,5)
    ssq += __shfl_xor(ssq, 16);
    ssq += __shfl_xor(ssq, 32);
    const float scalev = SCALE / fmaxf(sqrtf(ssq), EPSF);

    // ---- epilogue (wave-local). C/D: proto = nt*16 + m, pos-in-tile = quad*4 + r ----
    int vbits = 0;
#pragma unroll
    for (int nt = 0; nt < 16; ++nt) vbits |= validLds[nt * 16 + m] << nt;

    float scr[4];
#pragma unroll
    for (int r = 0; r < 4; ++r) scr[r] = __shfl(scalev, quad * 4 + r);   // lane quad*4+r holds pos w*16+quad*4+r
#pragma unroll
    for (int nt = 0; nt < 16; ++nt)
#pragma unroll
        for (int r = 0; r < 4; ++r) acc[nt][r] *= scr[r];   // positive factor: ordering-safe

#pragma unroll
    for (int r = 0; r < 4; ++r) {
        // pass 1: max / argmax (first occurrence) / 2nd-max
        float m1 = -INFINITY, m2 = -INFINITY; int id = 0x7fffffff;
#pragma unroll
        for (int nt = 0; nt < 16; ++nt) {
            if (vbits & (1 << nt)) {
                const float d = acc[nt][r];
                if (d > m1)      { m2 = m1; m1 = d; id = nt * 16 + m; }
                else if (d > m2) { m2 = d; }
            }
        }
#pragma unroll
        for (int sh = 1; sh < 16; sh <<= 1) {   // reduce over m (protos), within quad
            const float om1 = __shfl_xor(m1, sh);
            const float om2 = __shfl_xor(m2, sh);
            const int   oid = __shfl_xor(id, sh);
            if (om1 > m1) { m2 = fmaxf(m1, om2); m1 = om1; id = oid; }
            else { if (om1 == m1 && oid < id) id = oid; m2 = fmaxf(m2, om1); }
        }
        const int posg = b * HW + pos0 + w * 16 + quad * 4 + r;
        if (m == 0) {
            out[OUT_ASSIGN + posg] = (float)id;
            if (m1 - m2 < GAP_THRESH) {          // near-tie -> exact fp64 recheck
                const int slot = atomicAdd(counter, 1);
                if (slot < MAXSUS) suspects[slot] = posg;
            }
        }
        // pass 2: softmax denominator and weighted sum (all lanes hold m1)
        float se = 0.f, sw = 0.f;
#pragma unroll
        for (int nt = 0; nt < 16; ++nt) {
            if (vbits & (1 << nt)) {
                const float d = acc[nt][r];
                const float e = __expf(d - m1);
                se += e; sw = fmaf(e, d, sw);
            }
        }
#pragma unroll
        for (int sh = 1; sh < 16; sh <<= 1) {
            se += __shfl_xor(se, sh);
            sw += __shfl_xor(sw, sh);
        }
        if (m == 0) out[posg] = sw / se;
    }
}

// ---------------------------------------------------------------------------
// Recheck (R8 structure): one wave per suspect, grid-stride, uniform trip
// counts; lane l owns protos {l, l+64, l+128, l+192}; fp64 4-way split
// chains; first-occurrence tie-break.
// ---------------------------------------------------------------------------
__global__ __launch_bounds__(256)
void recheck_kernel(const float* __restrict__ qry, const double* __restrict__ pn64,
                    const int* __restrict__ valid, const int* __restrict__ counter,
                    const int* __restrict__ suspects, float* __restrict__ out)
{
    __shared__ float qsh[4][256];
    const int t = threadIdx.x;
    const int w = t >> 6, l = t & 63;
    int n = *counter; if (n > MAXSUS) n = MAXSUS;
    const int nb = (n + 3) >> 2;            // 4 suspects per block-iteration

    for (int batch = blockIdx.x; batch < nb; batch += gridDim.x) {
        const int si = batch * 4 + w;       // this wave's suspect
        const bool active = si < n;
        int pos = 0;
        if (active) {
            pos = suspects[si];
            // load q column: lane l loads c = l + 64*k into this wave's LDS row
#pragma unroll
            for (int k = 0; k < 4; ++k) {
                const int c = l + 64 * k;
                qsh[w][c] = qry[(size_t)(pos >> 12) * (C * HW) + (size_t)c * HW + (pos & (HW - 1))];
            }
        }
        __syncthreads();                    // qsh visible (uniform across block)
        if (active) {
            double best = -INFINITY; int bid = 0x7fffffff;
#pragma unroll
            for (int k = 0; k < 4; ++k) {
                const int p = l + 64 * k;   // increasing id order within lane
                if (valid[p]) {
                    const double* pr = pn64 + (size_t)p * C;
                    double a0 = 0.0, a1 = 0.0, a2 = 0.0, a3 = 0.0;
#pragma unroll 4
                    for (int c = 0; c < C; c += 4) {
                        a0 = fma((double)qsh[w][c + 0], pr[c + 0], a0);
                        a1 = fma((double)qsh[w][c + 1], pr[c + 1], a1);
                        a2 = fma((double)qsh[w][c + 2], pr[c + 2], a2);
                        a3 = fma((double)qsh[w][c + 3], pr[c + 3], a3);
                    }
                    const double d = (a0 + a1) + (a2 + a3);
                    if (d > best) { best = d; bid = p; }   // strict > keeps smallest id on ties
                }
            }
            // wave-wide reduce: max, smallest-id tie-break (first occurrence)
#pragma unroll
            for (int sh = 1; sh < 64; sh <<= 1) {
                const double od = __shfl_xor(best, sh);
                const int    oi = __shfl_xor(bid, sh);
                if (od > best || (od == best && oi < bid)) { best = od; bid = oi; }
            }
            if (l == 0) out[OUT_ASSIGN + pos] = (float)bid;
        }
        __syncthreads();                    // guard qsh overwrite next iteration
    }
}

// ---------------------------------------------------------------------------
extern "C" void kernel_launch(void* const* d_in, const int* in_sizes, int n_in,
                              void* d_out, int out_size, void* d_ws, size_t ws_size,
                              hipStream_t stream)
{
    const float* qry   = (const float*)d_in[0];
    const float* sup_x = (const float*)d_in[1];
    const float* sup_y = (const float*)d_in[2];
    float* out = (float*)d_out;
    char*  ws  = (char*)d_ws;

    // ws layout (~1.03 MiB total)
    unsigned short* pB       = (unsigned short*)(ws);            // 256 KiB frag-order split-bf16 protos
    double*         pn64     = (double*)(ws + 256 * 1024);       // 512 KiB
    int*            valid    = (int*)(ws + 768 * 1024);          // 1 KiB
    int*            counter  = (int*)(ws + 768 * 1024 + 1024);   // 4 B
    int*            suspects = (int*)(ws + 768 * 1024 + 2048);   // 256 KiB

    prep_kernel<<<dim3(P), dim3(256), 0, stream>>>(sup_x, sup_y, out, pB, pn64, valid, counter);
    dist_kernel<<<dim3(BQ * (HW / 64)), dim3(256), 0, stream>>>(qry, pB, valid, out, counter, suspects);
    recheck_kernel<<<dim3(1024), dim3(256), 0, stream>>>(qry, pn64, valid, counter, suspects, out);
}